// Round 6
// baseline (730.859 us; speedup 1.0000x reference)
//
#include <hip/hip_runtime.h>
#include <hip/hip_bf16.h>

// Rulebook sparse conv, R6.
//   pass2 rewritten: block = 64 consecutive out rows; stream the contiguous
//   sorted-vals range coalesced (16B/lane); per-rule row via 6-step binsearch
//   in LDS offs window; accumulate in padded [64][65] f32 LDS tile (ds_add);
//   write tile+bias once. No global atomics, no out-init kernel.
//   k_count re-vectorized (int4 loads, int4 rankl stores).

typedef __bf16 bf16x8_t __attribute__((ext_vector_type(8)));
typedef __bf16 bf16x2_t __attribute__((ext_vector_type(2)));
typedef float f32x4_t __attribute__((ext_vector_type(4)));

#define KOFF 27
#define RULES 50000
#define KR (KOFF * RULES) /* 1,350,000 */
#define CIN 64
#define COUT 64
#define NIN 150000
#define NOUT 150000
#define BR 256
#define BPK ((RULES + BR - 1) / BR) /* 196 */
#define P2ROWS 64

// ws layout (bytes, 256-aligned)
#define OFF_OFF 0ull          /* int off[NOUT+1] */
#define OFF_BSUM 600064ull    /* int bsum[147] */
#define OFF_RANK 600832ull    /* int rankl[KR] */
#define OFF_XB 6000896ull     /* bf16 xb[NIN][64] */
#define OFF_VALS_FULL 25200896ull /* bf16 vals[KR][64] */
#define OFF_VALS_MID 6000896ull   /* vals when no xb */
#define WS_FULL (25200896ull + 172800000ull) /* 198.0 MB */
#define WS_MID (6000896ull + 172800000ull)   /* 178.8 MB */

__device__ __forceinline__ void gload_lds16(const void* g, void* l) {
  __builtin_amdgcn_global_load_lds(
      (const __attribute__((address_space(1))) unsigned int*)g,
      (__attribute__((address_space(3))) unsigned int*)l, 16, 0, 0);
}

// ---------------- x -> bf16 ----------------
__global__ __launch_bounds__(256) void k_cvt(const float* __restrict__ x,
                                             __bf16* __restrict__ xb) {
  const int i = blockIdx.x * 256 + threadIdx.x;  // one per 8 elems
  if (i < NIN * CIN / 8) {
    const float4 f0 = reinterpret_cast<const float4*>(x)[i * 2];
    const float4 f1 = reinterpret_cast<const float4*>(x)[i * 2 + 1];
    bf16x8_t v;
    v[0] = (__bf16)f0.x; v[1] = (__bf16)f0.y; v[2] = (__bf16)f0.z; v[3] = (__bf16)f0.w;
    v[4] = (__bf16)f1.x; v[5] = (__bf16)f1.y; v[6] = (__bf16)f1.z; v[7] = (__bf16)f1.w;
    reinterpret_cast<bf16x8_t*>(xb)[i] = v;
  }
}

// ---------------- sort kernels ----------------
__global__ __launch_bounds__(256) void k_zero(int* __restrict__ cnt) {
  const int i = blockIdx.x * 256 + threadIdx.x;
  if (i < NOUT) cnt[i] = 0;
}

// counts AND per-rule arrival rank (coalesced int4 write)
__global__ __launch_bounds__(256) void k_count(const int* __restrict__ out_idx,
                                               int* __restrict__ cnt,
                                               int* __restrict__ rankl) {
  const int i = blockIdx.x * 256 + threadIdx.x;
  if (i < KR / 4) {
    const int4 v = reinterpret_cast<const int4*>(out_idx)[i];
    int4 r;
    r.x = atomicAdd(&cnt[v.x], 1);
    r.y = atomicAdd(&cnt[v.y], 1);
    r.z = atomicAdd(&cnt[v.z], 1);
    r.w = atomicAdd(&cnt[v.w], 1);
    reinterpret_cast<int4*>(rankl)[i] = r;
  }
}

__global__ __launch_bounds__(1024) void k_scan1(int* __restrict__ off,
                                                int* __restrict__ bsum) {
  __shared__ int s[1024];
  const int t = threadIdx.x;
  const int i = blockIdx.x * 1024 + t;
  const int v = (i < NOUT) ? off[i] : 0;
  s[t] = v;
  __syncthreads();
#pragma unroll
  for (int d = 1; d < 1024; d <<= 1) {
    const int u = (t >= d) ? s[t - d] : 0;
    __syncthreads();
    s[t] += u;
    __syncthreads();
  }
  if (i < NOUT) off[i] = s[t] - v;  // exclusive within block
  if (t == 1023) bsum[blockIdx.x] = s[1023];
}

__global__ __launch_bounds__(256) void k_scan2(int* __restrict__ bsum, int nb) {
  __shared__ int s[256];
  const int t = threadIdx.x;
  const int v = (t < nb) ? bsum[t] : 0;
  s[t] = v;
  __syncthreads();
#pragma unroll
  for (int d = 1; d < 256; d <<= 1) {
    const int u = (t >= d) ? s[t - d] : 0;
    __syncthreads();
    s[t] += u;
    __syncthreads();
  }
  if (t < nb) bsum[t] = s[t] - v;
}

__global__ __launch_bounds__(256) void k_scan3(int* __restrict__ off,
                                               const int* __restrict__ bsum) {
  const int i = blockIdx.x * 256 + threadIdx.x;
  if (i < NOUT) off[i] += bsum[i >> 10];
  if (i == 0) off[NOUT] = KR;
}

// ---------------- pass 1 (FULL): bf16 gather via global_load_lds ----------------
__global__ __launch_bounds__(256) void pass1_bf16(
    const __bf16* __restrict__ xb, const float* __restrict__ w,
    const int* __restrict__ in_idx, const int* __restrict__ out_idx,
    const int* __restrict__ off_arr, const int* __restrict__ rankl,
    __bf16* __restrict__ vals) {
  __shared__ char lds[256 * 128 + 64 * 128];
  char* const Abase = lds;
  char* const Bbase = lds + 256 * 128;

  const int bid = blockIdx.x;
  const int k = bid / BPK;
  const int rblk = bid - k * BPK;
  const int rule0 = rblk * BR;
  const int t = threadIdx.x;
  const int wid = t >> 6;
  const int lane = t & 63;

  // stage A: per-lane pre-swizzled source, linear LDS dest (m173 pattern)
  {
    const int rowInWave = lane >> 3;
    const int srcChunk = (lane & 7) ^ rowInWave;
    const int* idxBase = in_idx + (size_t)k * RULES;
#pragma unroll
    for (int it = 0; it < 8; ++it) {
      const int rbase = it * 32 + wid * 8;
      int rule = rule0 + rbase + rowInWave;
      if (rule > RULES - 1) rule = RULES - 1;  // clamp: finite data, skipped later
      const int src = idxBase[rule];
      const __bf16* gp = xb + ((size_t)src << 6) + (srcChunk << 3);
      gload_lds16(gp, Abase + rbase * 128 + lane * 16);
    }
  }

  // stage B: W_k^T -> LDS[o][c] bf16, swizzled
  {
    const int c = t >> 2;
    const int o0 = (t & 3) * 16;
    const float* wp = w + ((size_t)k * CIN + c) * COUT + o0;
#pragma unroll
    for (int j4 = 0; j4 < 4; ++j4) {
      const float4 f = *reinterpret_cast<const float4*>(wp + j4 * 4);
#pragma unroll
      for (int e = 0; e < 4; ++e) {
        const int o = o0 + j4 * 4 + e;
        const float val = (e == 0) ? f.x : (e == 1) ? f.y : (e == 2) ? f.z : f.w;
        const int addr = o * 128 + ((c * 2) ^ ((o & 7) << 4));
        *reinterpret_cast<__bf16*>(Bbase + addr) = (__bf16)val;
      }
    }
  }

  __syncthreads();

  const int rA = lane & 15;
  const int g = lane >> 4;

  bf16x8_t af[4][2];
  bf16x8_t bfr[4][2];
#pragma unroll
  for (int m = 0; m < 4; ++m)
#pragma unroll
    for (int kk = 0; kk < 2; ++kk) {
      const int r = wid * 64 + m * 16 + rA;
      const int colByte = (kk * 64 + g * 16) ^ ((r & 7) << 4);
      af[m][kk] = *reinterpret_cast<const bf16x8_t*>(Abase + r * 128 + colByte);
    }
#pragma unroll
  for (int n = 0; n < 4; ++n)
#pragma unroll
    for (int kk = 0; kk < 2; ++kk) {
      const int o = n * 16 + rA;
      const int colByte = (kk * 64 + g * 16) ^ ((o & 7) << 4);
      bfr[n][kk] = *reinterpret_cast<const bf16x8_t*>(Bbase + o * 128 + colByte);
    }

  __syncthreads();  // frag reads done; Abase reused for D staging

  f32x4_t acc[4][4];
#pragma unroll
  for (int m = 0; m < 4; ++m)
#pragma unroll
    for (int n = 0; n < 4; ++n)
#pragma unroll
      for (int e = 0; e < 4; ++e) acc[m][n][e] = 0.0f;

#pragma unroll
  for (int kk = 0; kk < 2; ++kk)
#pragma unroll
    for (int m = 0; m < 4; ++m)
#pragma unroll
      for (int n = 0; n < 4; ++n)
        acc[m][n] = __builtin_amdgcn_mfma_f32_16x16x32_bf16(
            af[m][kk], bfr[n][kk], acc[m][n], 0, 0, 0);

  // stage D -> LDS bf16 rows (swizzled)
  const bool evenLane = (rA & 1) == 0;
#pragma unroll
  for (int m = 0; m < 4; ++m) {
#pragma unroll
    for (int j = 0; j < 4; ++j) {
      const int rr = wid * 64 + m * 16 + g * 4 + j;
      float mine[4], other[4];
#pragma unroll
      for (int n = 0; n < 4; ++n) {
        mine[n] = acc[m][n][j];
        other[n] = __shfl_xor(mine[n], 1, 64);
      }
      const int swz = (rr & 7) << 4;
      if (evenLane) {
#pragma unroll
        for (int n = 0; n < 2; ++n) {
          bf16x2_t p; p[0] = (__bf16)mine[n]; p[1] = (__bf16)other[n];
          const int col = n * 16 + rA;
          *reinterpret_cast<bf16x2_t*>(Abase + rr * 128 + ((col * 2) ^ swz)) = p;
        }
      } else {
#pragma unroll
        for (int n = 2; n < 4; ++n) {
          bf16x2_t p; p[0] = (__bf16)other[n]; p[1] = (__bf16)mine[n];
          const int col = n * 16 + rA - 1;
          *reinterpret_cast<bf16x2_t*>(Abase + rr * 128 + ((col * 2) ^ swz)) = p;
        }
      }
    }
  }

  __syncthreads();

  // writeback: scatter full 128B rows to vals[off[o] + rankl[rule]]
  {
    const int chunk = t & 7;
    const int r0 = t >> 3;
#pragma unroll
    for (int pass = 0; pass < 8; ++pass) {
      const int r = r0 + pass * 32;
      const int rule = rule0 + r;
      if (rule < RULES) {
        const size_t gi = (size_t)k * RULES + rule;
        const int dst = off_arr[out_idx[gi]] + rankl[gi];
        const bf16x8_t v = *reinterpret_cast<const bf16x8_t*>(
            Abase + r * 128 + ((chunk * 16) ^ ((r & 7) << 4)));
        *reinterpret_cast<bf16x8_t*>(vals + (size_t)dst * COUT + chunk * 8) = v;
      }
    }
  }
}

// ---------------- pass 1 (MID): f32 gather, no xb ----------------
__global__ __launch_bounds__(256) void pass1_f32(
    const float* __restrict__ x, const float* __restrict__ w,
    const int* __restrict__ in_idx, const int* __restrict__ out_idx,
    const int* __restrict__ off_arr, const int* __restrict__ rankl,
    __bf16* __restrict__ vals) {
  __shared__ char lds[256 * 128 + 64 * 128];
  char* const Abase = lds;
  char* const Bbase = lds + 256 * 128;

  const int bid = blockIdx.x;
  const int k = bid / BPK;
  const int rblk = bid - k * BPK;
  const int rule0 = rblk * BR;
  const int t = threadIdx.x;

  {
    const int chunk = t & 7;
    const int r0 = t >> 3;
#pragma unroll
    for (int pass = 0; pass < 8; ++pass) {
      const int r = r0 + pass * 32;
      const int rule = rule0 + r;
      bf16x8_t v;
      if (rule < RULES) {
        const int src = in_idx[(size_t)k * RULES + rule];
        const float* p = x + (size_t)src * CIN + chunk * 8;
        const float4 f0 = *reinterpret_cast<const float4*>(p);
        const float4 f1 = *reinterpret_cast<const float4*>(p + 4);
        v[0] = (__bf16)f0.x; v[1] = (__bf16)f0.y;
        v[2] = (__bf16)f0.z; v[3] = (__bf16)f0.w;
        v[4] = (__bf16)f1.x; v[5] = (__bf16)f1.y;
        v[6] = (__bf16)f1.z; v[7] = (__bf16)f1.w;
      } else {
#pragma unroll
        for (int e = 0; e < 8; ++e) v[e] = (__bf16)0.0f;
      }
      const int colByte = (chunk * 16) ^ ((r & 7) << 4);
      *reinterpret_cast<bf16x8_t*>(Abase + r * 128 + colByte) = v;
    }
  }
  {
    const int c = t >> 2;
    const int o0 = (t & 3) * 16;
    const float* wp = w + ((size_t)k * CIN + c) * COUT + o0;
#pragma unroll
    for (int j4 = 0; j4 < 4; ++j4) {
      const float4 f = *reinterpret_cast<const float4*>(wp + j4 * 4);
#pragma unroll
      for (int e = 0; e < 4; ++e) {
        const int o = o0 + j4 * 4 + e;
        const float val = (e == 0) ? f.x : (e == 1) ? f.y : (e == 2) ? f.z : f.w;
        const int addr = o * 128 + ((c * 2) ^ ((o & 7) << 4));
        *reinterpret_cast<__bf16*>(Bbase + addr) = (__bf16)val;
      }
    }
  }
  __syncthreads();

  const int wid = t >> 6;
  const int l = t & 63;
  const int rA = l & 15;
  const int g = l >> 4;

  bf16x8_t af[4][2];
  bf16x8_t bfr[4][2];
#pragma unroll
  for (int m = 0; m < 4; ++m)
#pragma unroll
    for (int kk = 0; kk < 2; ++kk) {
      const int r = wid * 64 + m * 16 + rA;
      const int colByte = (kk * 64 + g * 16) ^ ((r & 7) << 4);
      af[m][kk] = *reinterpret_cast<const bf16x8_t*>(Abase + r * 128 + colByte);
    }
#pragma unroll
  for (int n = 0; n < 4; ++n)
#pragma unroll
    for (int kk = 0; kk < 2; ++kk) {
      const int o = n * 16 + rA;
      const int colByte = (kk * 64 + g * 16) ^ ((o & 7) << 4);
      bfr[n][kk] = *reinterpret_cast<const bf16x8_t*>(Bbase + o * 128 + colByte);
    }

  __syncthreads();

  f32x4_t acc[4][4];
#pragma unroll
  for (int m = 0; m < 4; ++m)
#pragma unroll
    for (int n = 0; n < 4; ++n)
#pragma unroll
      for (int e = 0; e < 4; ++e) acc[m][n][e] = 0.0f;

#pragma unroll
  for (int kk = 0; kk < 2; ++kk)
#pragma unroll
    for (int m = 0; m < 4; ++m)
#pragma unroll
      for (int n = 0; n < 4; ++n)
        acc[m][n] = __builtin_amdgcn_mfma_f32_16x16x32_bf16(
            af[m][kk], bfr[n][kk], acc[m][n], 0, 0, 0);

  const bool evenLane = (rA & 1) == 0;
#pragma unroll
  for (int m = 0; m < 4; ++m) {
#pragma unroll
    for (int j = 0; j < 4; ++j) {
      const int rr = wid * 64 + m * 16 + g * 4 + j;
      float mine[4], other[4];
#pragma unroll
      for (int n = 0; n < 4; ++n) {
        mine[n] = acc[m][n][j];
        other[n] = __shfl_xor(mine[n], 1, 64);
      }
      const int swz = (rr & 7) << 4;
      if (evenLane) {
#pragma unroll
        for (int n = 0; n < 2; ++n) {
          bf16x2_t p; p[0] = (__bf16)mine[n]; p[1] = (__bf16)other[n];
          const int col = n * 16 + rA;
          *reinterpret_cast<bf16x2_t*>(Abase + rr * 128 + ((col * 2) ^ swz)) = p;
        }
      } else {
#pragma unroll
        for (int n = 2; n < 4; ++n) {
          bf16x2_t p; p[0] = (__bf16)other[n]; p[1] = (__bf16)mine[n];
          const int col = n * 16 + rA - 1;
          *reinterpret_cast<bf16x2_t*>(Abase + rr * 128 + ((col * 2) ^ swz)) = p;
        }
      }
    }
  }

  __syncthreads();

  {
    const int chunk = t & 7;
    const int r0 = t >> 3;
#pragma unroll
    for (int pass = 0; pass < 8; ++pass) {
      const int r = r0 + pass * 32;
      const int rule = rule0 + r;
      if (rule < RULES) {
        const size_t gi = (size_t)k * RULES + rule;
        const int dst = off_arr[out_idx[gi]] + rankl[gi];
        const bf16x8_t v = *reinterpret_cast<const bf16x8_t*>(
            Abase + r * 128 + ((chunk * 16) ^ ((r & 7) << 4)));
        *reinterpret_cast<bf16x8_t*>(vals + (size_t)dst * COUT + chunk * 8) = v;
      }
    }
  }
}

// ---------------- pass 2 v2: row-tiled LDS-accumulate streamer ----------------
__global__ __launch_bounds__(256) void pass2_kernel(
    const __bf16* __restrict__ vals, const int* __restrict__ off,
    const float* __restrict__ bias, float* __restrict__ out) {
  __shared__ int offs[P2ROWS + 1];
  __shared__ float acc[P2ROWS][65];  // pad 65: bank = (row+ch)&31

  const int t = threadIdx.x;
  const int row0 = blockIdx.x * P2ROWS;

  if (t <= P2ROWS) {
    int r = row0 + t;
    if (r > NOUT) r = NOUT;
    offs[t] = off[r];
  }
  for (int i = t; i < P2ROWS * 65; i += 256)
    (&acc[0][0])[i] = 0.0f;
  __syncthreads();

  const int S = offs[0];
  const int E = offs[P2ROWS];
  const int chunk = t & 7;   // 8 channels each
  const int q = t >> 3;      // rule-lane 0..31

  for (int j = S + q; j < E; j += 32) {
    const bf16x8_t v =
        *reinterpret_cast<const bf16x8_t*>(vals + (size_t)j * COUT + chunk * 8);
    // binary search: largest row with offs[row] <= j
    int lo = 0, hi = P2ROWS;
    while (hi - lo > 1) {
      const int mid = (lo + hi) >> 1;
      if (j >= offs[mid]) lo = mid; else hi = mid;
    }
#pragma unroll
    for (int e = 0; e < 8; ++e)
      atomicAdd(&acc[lo][chunk * 8 + e], (float)v[e]);
  }

  __syncthreads();

  // write out: thread -> (row = t>>2, 16 ch)
  {
    const int r = t >> 2;
    const int c0 = (t & 3) * 16;
    if (row0 + r < NOUT) {
      float* op = out + (size_t)(row0 + r) * COUT + c0;
#pragma unroll
      for (int v4 = 0; v4 < 4; ++v4) {
        const float4 b = reinterpret_cast<const float4*>(bias)[(c0 >> 2) + v4];
        float4 o;
        o.x = acc[r][c0 + v4 * 4 + 0] + b.x;
        o.y = acc[r][c0 + v4 * 4 + 1] + b.y;
        o.z = acc[r][c0 + v4 * 4 + 2] + b.z;
        o.w = acc[r][c0 + v4 * 4 + 3] + b.w;
        reinterpret_cast<float4*>(op)[v4] = o;
      }
    }
  }
}

// ---------------- fallback (tiny ws): atomic scatter ----------------
__global__ __launch_bounds__(256) void init_out_kernel(
    const float* __restrict__ bias, float* __restrict__ out, int total4) {
  const int i = blockIdx.x * blockDim.x + threadIdx.x;
  if (i < total4) {
    const float4 v = reinterpret_cast<const float4*>(bias)[i & 15];
    reinterpret_cast<float4*>(out)[i] = v;
  }
}

__global__ __launch_bounds__(256) void spconv_atomic_kernel(
    const float* __restrict__ x, const float* __restrict__ w,
    const int* __restrict__ in_idx, const int* __restrict__ out_idx,
    float* __restrict__ out) {
  __shared__ char lds[256 * 128 + 64 * 128];
  char* const Abase = lds;
  char* const Bbase = lds + 256 * 128;

  const int bid = blockIdx.x;
  const int k = bid / BPK;
  const int rblk = bid - k * BPK;
  const int rule0 = rblk * BR;
  const int t = threadIdx.x;

  {
    const int chunk = t & 7;
    const int r0 = t >> 3;
#pragma unroll
    for (int pass = 0; pass < 8; ++pass) {
      const int r = r0 + pass * 32;
      const int rule = rule0 + r;
      bf16x8_t v;
      if (rule < RULES) {
        const int src = in_idx[(size_t)k * RULES + rule];
        const float* p = x + (size_t)src * CIN + chunk * 8;
        const float4 f0 = *reinterpret_cast<const float4*>(p);
        const float4 f1 = *reinterpret_cast<const float4*>(p + 4);
        v[0] = (__bf16)f0.x; v[1] = (__bf16)f0.y;
        v[2] = (__bf16)f0.z; v[3] = (__bf16)f0.w;
        v[4] = (__bf16)f1.x; v[5] = (__bf16)f1.y;
        v[6] = (__bf16)f1.z; v[7] = (__bf16)f1.w;
      } else {
#pragma unroll
        for (int e = 0; e < 8; ++e) v[e] = (__bf16)0.0f;
      }
      const int colByte = (chunk * 16) ^ ((r & 7) << 4);
      *reinterpret_cast<bf16x8_t*>(Abase + r * 128 + colByte) = v;
    }
  }
  {
    const int c = t >> 2;
    const int o0 = (t & 3) * 16;
    const float* wp = w + ((size_t)k * CIN + c) * COUT + o0;
#pragma unroll
    for (int j4 = 0; j4 < 4; ++j4) {
      const float4 f = *reinterpret_cast<const float4*>(wp + j4 * 4);
#pragma unroll
      for (int e = 0; e < 4; ++e) {
        const int o = o0 + j4 * 4 + e;
        const float val = (e == 0) ? f.x : (e == 1) ? f.y : (e == 2) ? f.z : f.w;
        const int addr = o * 128 + ((c * 2) ^ ((o & 7) << 4));
        *reinterpret_cast<__bf16*>(Bbase + addr) = (__bf16)val;
      }
    }
  }
  __syncthreads();

  const int wid = t >> 6;
  const int l = t & 63;
  const int rA = l & 15;
  const int g = l >> 4;

  bf16x8_t af[4][2];
  bf16x8_t bfr[4][2];
#pragma unroll
  for (int m = 0; m < 4; ++m)
#pragma unroll
    for (int kk = 0; kk < 2; ++kk) {
      const int r = wid * 64 + m * 16 + rA;
      const int colByte = (kk * 64 + g * 16) ^ ((r & 7) << 4);
      af[m][kk] = *reinterpret_cast<const bf16x8_t*>(Abase + r * 128 + colByte);
    }
#pragma unroll
  for (int n = 0; n < 4; ++n)
#pragma unroll
    for (int kk = 0; kk < 2; ++kk) {
      const int o = n * 16 + rA;
      const int colByte = (kk * 64 + g * 16) ^ ((o & 7) << 4);
      bfr[n][kk] = *reinterpret_cast<const bf16x8_t*>(Bbase + o * 128 + colByte);
    }

  f32x4_t acc[4][4];
#pragma unroll
  for (int m = 0; m < 4; ++m)
#pragma unroll
    for (int n = 0; n < 4; ++n)
#pragma unroll
      for (int e = 0; e < 4; ++e) acc[m][n][e] = 0.0f;

#pragma unroll
  for (int kk = 0; kk < 2; ++kk)
#pragma unroll
    for (int m = 0; m < 4; ++m)
#pragma unroll
      for (int n = 0; n < 4; ++n)
        acc[m][n] = __builtin_amdgcn_mfma_f32_16x16x32_bf16(
            af[m][kk], bfr[n][kk], acc[m][n], 0, 0, 0);

#pragma unroll
  for (int m = 0; m < 4; ++m)
#pragma unroll
    for (int j = 0; j < 4; ++j) {
      const int rr = wid * 64 + m * 16 + g * 4 + j;
      const int rule = rule0 + rr;
      if (rule < RULES) {
        const int orow = out_idx[(size_t)k * RULES + rule];
        float* op = out + (size_t)orow * COUT + rA;
#pragma unroll
        for (int n = 0; n < 4; ++n) atomicAdd(op + n * 16, acc[m][n][j]);
      }
    }
}

// ---------------- launch ----------------
extern "C" void kernel_launch(void* const* d_in, const int* in_sizes, int n_in,
                              void* d_out, int out_size, void* d_ws, size_t ws_size,
                              hipStream_t stream) {
  const float* x = (const float*)d_in[0];
  const float* w = (const float*)d_in[1];
  const float* bias = (const float*)d_in[2];
  const int* in_idx = (const int*)d_in[3];
  const int* out_idx = (const int*)d_in[4];
  float* out = (float*)d_out;

  if (ws_size >= WS_MID) {
    char* ws = (char*)d_ws;
    int* off = (int*)(ws + OFF_OFF);
    int* bsum = (int*)(ws + OFF_BSUM);
    int* rankl = (int*)(ws + OFF_RANK);
    const bool full = (ws_size >= WS_FULL);
    __bf16* xb = (__bf16*)(ws + OFF_XB);
    __bf16* vals = (__bf16*)(ws + (full ? OFF_VALS_FULL : OFF_VALS_MID));

    const int nb1 = (NOUT + 1023) / 1024;  // 147
    if (full) k_cvt<<<(NIN * CIN / 8 + 255) / 256, 256, 0, stream>>>(x, xb);
    k_zero<<<(NOUT + 255) / 256, 256, 0, stream>>>(off);
    k_count<<<(KR / 4 + 255) / 256, 256, 0, stream>>>(out_idx, off, rankl);
    k_scan1<<<nb1, 1024, 0, stream>>>(off, bsum);
    k_scan2<<<1, 256, 0, stream>>>(bsum, nb1);
    k_scan3<<<(NOUT + 255) / 256, 256, 0, stream>>>(off, bsum);
    if (full) {
      pass1_bf16<<<KOFF * BPK, 256, 0, stream>>>(xb, w, in_idx, out_idx, off,
                                                 rankl, vals);
    } else {
      pass1_f32<<<KOFF * BPK, 256, 0, stream>>>(x, w, in_idx, out_idx, off,
                                                rankl, vals);
    }
    pass2_kernel<<<(NOUT + P2ROWS - 1) / P2ROWS, 256, 0, stream>>>(vals, off,
                                                                   bias, out);
  } else {
    const int total4 = NOUT * COUT / 4;
    init_out_kernel<<<(total4 + 255) / 256, 256, 0, stream>>>(bias, out, total4);
    spconv_atomic_kernel<<<KOFF * BPK, 256, 0, stream>>>(x, w, in_idx, out_idx, out);
  }
}

// Round 7
// 274.128 us; speedup vs baseline: 2.6661x; 2.6661x over previous
//
#include <hip/hip_runtime.h>
#include <hip/hip_bf16.h>

// Rulebook sparse conv, R7.
//   R6 lesson: LDS f32 atomic accumulate = 175 G ops/s (worse than global
//   atomics). pass2 reverted to register-accumulate: thread=(row, 4ch),
//   wave = 4 rows x 16 lanes, 8B/lane coalesced reads, zero atomics.
//   pass1: BR 256->128 (LDS 40->24KB, 6 blocks/CU) for latency hiding.
//   k_zero fused into k_cvt.

typedef __bf16 bf16x8_t __attribute__((ext_vector_type(8)));
typedef __bf16 bf16x4_t __attribute__((ext_vector_type(4)));
typedef __bf16 bf16x2_t __attribute__((ext_vector_type(2)));
typedef float f32x4_t __attribute__((ext_vector_type(4)));

#define KOFF 27
#define RULES 50000
#define KR (KOFF * RULES) /* 1,350,000 */
#define CIN 64
#define COUT 64
#define NIN 150000
#define NOUT 150000

// pass1 tile
#define BR1 128
#define BPK1 ((RULES + BR1 - 1) / BR1) /* 391 */
// fallback tile
#define BRF 256
#define BPKF ((RULES + BRF - 1) / BRF) /* 196 */

// ws layout (bytes, 256-aligned)
#define OFF_OFF 0ull          /* int off[NOUT+1] */
#define OFF_BSUM 600064ull    /* int bsum[147] */
#define OFF_RANK 600832ull    /* int rankl[KR] */
#define OFF_XB 6000896ull     /* bf16 xb[NIN][64] */
#define OFF_VALS 25200896ull  /* bf16 vals[KR][64] */
#define WS_FULL (25200896ull + 172800000ull) /* 198.0 MB */

__device__ __forceinline__ void gload_lds16(const void* g, void* l) {
  __builtin_amdgcn_global_load_lds(
      (const __attribute__((address_space(1))) unsigned int*)g,
      (__attribute__((address_space(3))) unsigned int*)l, 16, 0, 0);
}

// ---------------- x -> bf16, fused with off zeroing ----------------
__global__ __launch_bounds__(256) void k_cvt_zero(const float* __restrict__ x,
                                                  __bf16* __restrict__ xb,
                                                  int* __restrict__ cnt) {
  const int i = blockIdx.x * 256 + threadIdx.x;
  if (i < NIN * CIN / 8) {
    const float4 f0 = reinterpret_cast<const float4*>(x)[i * 2];
    const float4 f1 = reinterpret_cast<const float4*>(x)[i * 2 + 1];
    bf16x8_t v;
    v[0] = (__bf16)f0.x; v[1] = (__bf16)f0.y; v[2] = (__bf16)f0.z; v[3] = (__bf16)f0.w;
    v[4] = (__bf16)f1.x; v[5] = (__bf16)f1.y; v[6] = (__bf16)f1.z; v[7] = (__bf16)f1.w;
    reinterpret_cast<bf16x8_t*>(xb)[i] = v;
  }
  if (i <= NOUT) cnt[i] = 0;
}

// ---------------- sort kernels ----------------
// counts AND per-rule arrival rank (int4 coalesced)
__global__ __launch_bounds__(256) void k_count(const int* __restrict__ out_idx,
                                               int* __restrict__ cnt,
                                               int* __restrict__ rankl) {
  const int i = blockIdx.x * 256 + threadIdx.x;
  if (i < KR / 4) {
    const int4 v = reinterpret_cast<const int4*>(out_idx)[i];
    int4 r;
    r.x = atomicAdd(&cnt[v.x], 1);
    r.y = atomicAdd(&cnt[v.y], 1);
    r.z = atomicAdd(&cnt[v.z], 1);
    r.w = atomicAdd(&cnt[v.w], 1);
    reinterpret_cast<int4*>(rankl)[i] = r;
  }
}

__global__ __launch_bounds__(1024) void k_scan1(int* __restrict__ off,
                                                int* __restrict__ bsum) {
  __shared__ int s[1024];
  const int t = threadIdx.x;
  const int i = blockIdx.x * 1024 + t;
  const int v = (i < NOUT) ? off[i] : 0;
  s[t] = v;
  __syncthreads();
#pragma unroll
  for (int d = 1; d < 1024; d <<= 1) {
    const int u = (t >= d) ? s[t - d] : 0;
    __syncthreads();
    s[t] += u;
    __syncthreads();
  }
  if (i < NOUT) off[i] = s[t] - v;  // exclusive within block
  if (t == 1023) bsum[blockIdx.x] = s[1023];
}

__global__ __launch_bounds__(256) void k_scan2(int* __restrict__ bsum, int nb) {
  __shared__ int s[256];
  const int t = threadIdx.x;
  const int v = (t < nb) ? bsum[t] : 0;
  s[t] = v;
  __syncthreads();
#pragma unroll
  for (int d = 1; d < 256; d <<= 1) {
    const int u = (t >= d) ? s[t - d] : 0;
    __syncthreads();
    s[t] += u;
    __syncthreads();
  }
  if (t < nb) bsum[t] = s[t] - v;
}

__global__ __launch_bounds__(256) void k_scan3(int* __restrict__ off,
                                               const int* __restrict__ bsum) {
  const int i = blockIdx.x * 256 + threadIdx.x;
  if (i < NOUT) off[i] += bsum[i >> 10];
  if (i == 0) off[NOUT] = KR;
}

// ---------------- pass 1: bf16 gather via global_load_lds, BR=128 ----------------
__global__ __launch_bounds__(256) void pass1_bf16(
    const __bf16* __restrict__ xb, const float* __restrict__ w,
    const int* __restrict__ in_idx, const int* __restrict__ out_idx,
    const int* __restrict__ off_arr, const int* __restrict__ rankl,
    __bf16* __restrict__ vals) {
  __shared__ char lds[BR1 * 128 + 64 * 128];  // 24 KB
  char* const Abase = lds;
  char* const Bbase = lds + BR1 * 128;

  const int bid = blockIdx.x;
  const int k = bid / BPK1;
  const int rblk = bid - k * BPK1;
  const int rule0 = rblk * BR1;
  const int t = threadIdx.x;
  const int wid = t >> 6;
  const int lane = t & 63;

  // stage A: per-lane pre-swizzled source, linear LDS dest
  {
    const int rowInWave = lane >> 3;
    const int srcChunk = (lane & 7) ^ rowInWave;
    const int* idxBase = in_idx + (size_t)k * RULES;
#pragma unroll
    for (int it = 0; it < 4; ++it) {
      const int rbase = it * 32 + wid * 8;
      int rule = rule0 + rbase + rowInWave;
      if (rule > RULES - 1) rule = RULES - 1;  // clamp: finite data, skipped later
      const int src = idxBase[rule];
      const __bf16* gp = xb + ((size_t)src << 6) + (srcChunk << 3);
      gload_lds16(gp, Abase + rbase * 128 + lane * 16);
    }
  }

  // stage B: W_k^T -> LDS[o][c] bf16, swizzled
  {
    const int c = t >> 2;
    const int o0 = (t & 3) * 16;
    const float* wp = w + ((size_t)k * CIN + c) * COUT + o0;
#pragma unroll
    for (int j4 = 0; j4 < 4; ++j4) {
      const float4 f = *reinterpret_cast<const float4*>(wp + j4 * 4);
#pragma unroll
      for (int e = 0; e < 4; ++e) {
        const int o = o0 + j4 * 4 + e;
        const float val = (e == 0) ? f.x : (e == 1) ? f.y : (e == 2) ? f.z : f.w;
        const int addr = o * 128 + ((c * 2) ^ ((o & 7) << 4));
        *reinterpret_cast<__bf16*>(Bbase + addr) = (__bf16)val;
      }
    }
  }

  __syncthreads();

  const int rA = lane & 15;
  const int g = lane >> 4;

  bf16x8_t af[2][2];
  bf16x8_t bfr[4][2];
#pragma unroll
  for (int m = 0; m < 2; ++m)
#pragma unroll
    for (int kk = 0; kk < 2; ++kk) {
      const int r = wid * 32 + m * 16 + rA;
      const int colByte = (kk * 64 + g * 16) ^ ((r & 7) << 4);
      af[m][kk] = *reinterpret_cast<const bf16x8_t*>(Abase + r * 128 + colByte);
    }
#pragma unroll
  for (int n = 0; n < 4; ++n)
#pragma unroll
    for (int kk = 0; kk < 2; ++kk) {
      const int o = n * 16 + rA;
      const int colByte = (kk * 64 + g * 16) ^ ((o & 7) << 4);
      bfr[n][kk] = *reinterpret_cast<const bf16x8_t*>(Bbase + o * 128 + colByte);
    }

  __syncthreads();  // frag reads done; Abase reused for D staging

  f32x4_t acc[2][4];
#pragma unroll
  for (int m = 0; m < 2; ++m)
#pragma unroll
    for (int n = 0; n < 4; ++n)
#pragma unroll
      for (int e = 0; e < 4; ++e) acc[m][n][e] = 0.0f;

#pragma unroll
  for (int kk = 0; kk < 2; ++kk)
#pragma unroll
    for (int m = 0; m < 2; ++m)
#pragma unroll
      for (int n = 0; n < 4; ++n)
        acc[m][n] = __builtin_amdgcn_mfma_f32_16x16x32_bf16(
            af[m][kk], bfr[n][kk], acc[m][n], 0, 0, 0);

  // stage D -> LDS bf16 rows (swizzled)
  const bool evenLane = (rA & 1) == 0;
#pragma unroll
  for (int m = 0; m < 2; ++m) {
#pragma unroll
    for (int j = 0; j < 4; ++j) {
      const int rr = wid * 32 + m * 16 + g * 4 + j;
      float mine[4], other[4];
#pragma unroll
      for (int n = 0; n < 4; ++n) {
        mine[n] = acc[m][n][j];
        other[n] = __shfl_xor(mine[n], 1, 64);
      }
      const int swz = (rr & 7) << 4;
      if (evenLane) {
#pragma unroll
        for (int n = 0; n < 2; ++n) {
          bf16x2_t p; p[0] = (__bf16)mine[n]; p[1] = (__bf16)other[n];
          const int col = n * 16 + rA;
          *reinterpret_cast<bf16x2_t*>(Abase + rr * 128 + ((col * 2) ^ swz)) = p;
        }
      } else {
#pragma unroll
        for (int n = 2; n < 4; ++n) {
          bf16x2_t p; p[0] = (__bf16)other[n]; p[1] = (__bf16)mine[n];
          const int col = n * 16 + rA - 1;
          *reinterpret_cast<bf16x2_t*>(Abase + rr * 128 + ((col * 2) ^ swz)) = p;
        }
      }
    }
  }

  __syncthreads();

  // writeback: scatter full 128B rows to vals[off[o] + rankl[rule]]
  {
    const int chunk = t & 7;
    const int r0 = t >> 3;
#pragma unroll
    for (int pass = 0; pass < 4; ++pass) {
      const int r = r0 + pass * 32;
      const int rule = rule0 + r;
      if (rule < RULES) {
        const size_t gi = (size_t)k * RULES + rule;
        const int dst = off_arr[out_idx[gi]] + rankl[gi];
        const bf16x8_t v = *reinterpret_cast<const bf16x8_t*>(
            Abase + r * 128 + ((chunk * 16) ^ ((r & 7) << 4)));
        *reinterpret_cast<bf16x8_t*>(vals + (size_t)dst * COUT + chunk * 8) = v;
      }
    }
  }
}

// ---------------- pass 2 v3: register-accumulate segment reduce ----------------
// thread = (row, 4-channel slice); wave = 4 rows x 16 lanes; 8B/lane reads.
__global__ __launch_bounds__(256) void pass2_kernel(
    const __bf16* __restrict__ vals, const int* __restrict__ off,
    const float* __restrict__ bias, float* __restrict__ out) {
  const int t = threadIdx.x;
  const int rloc = t >> 4;   // 0..15
  const int l16 = t & 15;    // channel slice (4 ch)
  const int row = blockIdx.x * 16 + rloc;
  if (row >= NOUT) return;

  const float4 b = reinterpret_cast<const float4*>(bias)[l16];
  float a0 = b.x, a1 = b.y, a2 = b.z, a3 = b.w;

  const int r0 = off[row];
  const int r1 = off[row + 1];
  const __bf16* vp = vals + (size_t)r0 * COUT + l16 * 4;
  for (int j = r0; j < r1; ++j, vp += COUT) {
    const bf16x4_t v = *reinterpret_cast<const bf16x4_t*>(vp);
    a0 += (float)v[0];
    a1 += (float)v[1];
    a2 += (float)v[2];
    a3 += (float)v[3];
  }
  reinterpret_cast<float4*>(out + (size_t)row * COUT)[l16] =
      make_float4(a0, a1, a2, a3);
}

// ---------------- fallback (tiny ws): atomic scatter ----------------
__global__ __launch_bounds__(256) void init_out_kernel(
    const float* __restrict__ bias, float* __restrict__ out, int total4) {
  const int i = blockIdx.x * blockDim.x + threadIdx.x;
  if (i < total4) {
    const float4 v = reinterpret_cast<const float4*>(bias)[i & 15];
    reinterpret_cast<float4*>(out)[i] = v;
  }
}

__global__ __launch_bounds__(256) void spconv_atomic_kernel(
    const float* __restrict__ x, const float* __restrict__ w,
    const int* __restrict__ in_idx, const int* __restrict__ out_idx,
    float* __restrict__ out) {
  __shared__ char lds[256 * 128 + 64 * 128];
  char* const Abase = lds;
  char* const Bbase = lds + 256 * 128;

  const int bid = blockIdx.x;
  const int k = bid / BPKF;
  const int rblk = bid - k * BPKF;
  const int rule0 = rblk * BRF;
  const int t = threadIdx.x;

  {
    const int chunk = t & 7;
    const int r0 = t >> 3;
#pragma unroll
    for (int pass = 0; pass < 8; ++pass) {
      const int r = r0 + pass * 32;
      const int rule = rule0 + r;
      bf16x8_t v;
      if (rule < RULES) {
        const int src = in_idx[(size_t)k * RULES + rule];
        const float* p = x + (size_t)src * CIN + chunk * 8;
        const float4 f0 = *reinterpret_cast<const float4*>(p);
        const float4 f1 = *reinterpret_cast<const float4*>(p + 4);
        v[0] = (__bf16)f0.x; v[1] = (__bf16)f0.y;
        v[2] = (__bf16)f0.z; v[3] = (__bf16)f0.w;
        v[4] = (__bf16)f1.x; v[5] = (__bf16)f1.y;
        v[6] = (__bf16)f1.z; v[7] = (__bf16)f1.w;
      } else {
#pragma unroll
        for (int e = 0; e < 8; ++e) v[e] = (__bf16)0.0f;
      }
      const int colByte = (chunk * 16) ^ ((r & 7) << 4);
      *reinterpret_cast<bf16x8_t*>(Abase + r * 128 + colByte) = v;
    }
  }
  {
    const int c = t >> 2;
    const int o0 = (t & 3) * 16;
    const float* wp = w + ((size_t)k * CIN + c) * COUT + o0;
#pragma unroll
    for (int j4 = 0; j4 < 4; ++j4) {
      const float4 f = *reinterpret_cast<const float4*>(wp + j4 * 4);
#pragma unroll
      for (int e = 0; e < 4; ++e) {
        const int o = o0 + j4 * 4 + e;
        const float val = (e == 0) ? f.x : (e == 1) ? f.y : (e == 2) ? f.z : f.w;
        const int addr = o * 128 + ((c * 2) ^ ((o & 7) << 4));
        *reinterpret_cast<__bf16*>(Bbase + addr) = (__bf16)val;
      }
    }
  }
  __syncthreads();

  const int wid = t >> 6;
  const int l = t & 63;
  const int rA = l & 15;
  const int g = l >> 4;

  bf16x8_t af[4][2];
  bf16x8_t bfr[4][2];
#pragma unroll
  for (int m = 0; m < 4; ++m)
#pragma unroll
    for (int kk = 0; kk < 2; ++kk) {
      const int r = wid * 64 + m * 16 + rA;
      const int colByte = (kk * 64 + g * 16) ^ ((r & 7) << 4);
      af[m][kk] = *reinterpret_cast<const bf16x8_t*>(Abase + r * 128 + colByte);
    }
#pragma unroll
  for (int n = 0; n < 4; ++n)
#pragma unroll
    for (int kk = 0; kk < 2; ++kk) {
      const int o = n * 16 + rA;
      const int colByte = (kk * 64 + g * 16) ^ ((o & 7) << 4);
      bfr[n][kk] = *reinterpret_cast<const bf16x8_t*>(Bbase + o * 128 + colByte);
    }

  f32x4_t acc[4][4];
#pragma unroll
  for (int m = 0; m < 4; ++m)
#pragma unroll
    for (int n = 0; n < 4; ++n)
#pragma unroll
      for (int e = 0; e < 4; ++e) acc[m][n][e] = 0.0f;

#pragma unroll
  for (int kk = 0; kk < 2; ++kk)
#pragma unroll
    for (int m = 0; m < 4; ++m)
#pragma unroll
      for (int n = 0; n < 4; ++n)
        acc[m][n] = __builtin_amdgcn_mfma_f32_16x16x32_bf16(
            af[m][kk], bfr[n][kk], acc[m][n], 0, 0, 0);

#pragma unroll
  for (int m = 0; m < 4; ++m)
#pragma unroll
    for (int j = 0; j < 4; ++j) {
      const int rr = wid * 64 + m * 16 + g * 4 + j;
      const int rule = rule0 + rr;
      if (rule < RULES) {
        const int orow = out_idx[(size_t)k * RULES + rule];
        float* op = out + (size_t)orow * COUT + rA;
#pragma unroll
        for (int n = 0; n < 4; ++n) atomicAdd(op + n * 16, acc[m][n][j]);
      }
    }
}

// ---------------- launch ----------------
extern "C" void kernel_launch(void* const* d_in, const int* in_sizes, int n_in,
                              void* d_out, int out_size, void* d_ws, size_t ws_size,
                              hipStream_t stream) {
  const float* x = (const float*)d_in[0];
  const float* w = (const float*)d_in[1];
  const float* bias = (const float*)d_in[2];
  const int* in_idx = (const int*)d_in[3];
  const int* out_idx = (const int*)d_in[4];
  float* out = (float*)d_out;

  if (ws_size >= WS_FULL) {
    char* ws = (char*)d_ws;
    int* off = (int*)(ws + OFF_OFF);
    int* bsum = (int*)(ws + OFF_BSUM);
    int* rankl = (int*)(ws + OFF_RANK);
    __bf16* xb = (__bf16*)(ws + OFF_XB);
    __bf16* vals = (__bf16*)(ws + OFF_VALS);

    const int nb1 = (NOUT + 1023) / 1024;  // 147
    k_cvt_zero<<<(NIN * CIN / 8 + 255) / 256, 256, 0, stream>>>(x, xb, off);
    k_count<<<(KR / 4 + 255) / 256, 256, 0, stream>>>(out_idx, off, rankl);
    k_scan1<<<nb1, 1024, 0, stream>>>(off, bsum);
    k_scan2<<<1, 256, 0, stream>>>(bsum, nb1);
    k_scan3<<<(NOUT + 255) / 256, 256, 0, stream>>>(off, bsum);
    pass1_bf16<<<KOFF * BPK1, 256, 0, stream>>>(xb, w, in_idx, out_idx, off,
                                                rankl, vals);
    pass2_kernel<<<(NOUT + 15) / 16, 256, 0, stream>>>(vals, off, bias, out);
  } else {
    const int total4 = NOUT * COUT / 4;
    init_out_kernel<<<(total4 + 255) / 256, 256, 0, stream>>>(bias, out, total4);
    spconv_atomic_kernel<<<KOFF * BPKF, 256, 0, stream>>>(x, w, in_idx, out_idx, out);
  }
}

// Round 8
// 261.927 us; speedup vs baseline: 2.7903x; 1.0466x over previous
//
#include <hip/hip_runtime.h>
#include <hip/hip_bf16.h>

// Rulebook sparse conv, R8.
//   - pass2 v4: chunk-stream sorted vals into LDS via global_load_lds
//     (coalesced 16B/lane), register-accumulate per (row,4ch). Divergence
//     cost moves HBM->LDS. Zero atomics (R6: LDS atomics = 175 G/s trap).
//   - pass1: writeback dst precomputed into LDS during stage-A (kills the
//     end-of-kernel dependent load chain).
//   - k_scan2 merged into k_scan3 (each block re-scans 147 bsums in LDS).

typedef __bf16 bf16x8_t __attribute__((ext_vector_type(8)));
typedef __bf16 bf16x4_t __attribute__((ext_vector_type(4)));
typedef __bf16 bf16x2_t __attribute__((ext_vector_type(2)));
typedef float f32x4_t __attribute__((ext_vector_type(4)));

#define KOFF 27
#define RULES 50000
#define KR (KOFF * RULES) /* 1,350,000 */
#define CIN 64
#define COUT 64
#define NIN 150000
#define NOUT 150000

// pass1 tile
#define BR1 128
#define BPK1 ((RULES + BR1 - 1) / BR1) /* 391 */
// pass2 tile
#define P2R 16    /* out rows per block */
#define P2CH 256  /* rules per LDS chunk (32 KB) */
// fallback tile
#define BRF 256
#define BPKF ((RULES + BRF - 1) / BRF) /* 196 */

// ws layout (bytes, 256-aligned)
#define OFF_OFF 0ull          /* int off[NOUT+1] */
#define OFF_BSUM 600064ull    /* int bsum[147] */
#define OFF_RANK 600832ull    /* int rankl[KR] */
#define OFF_XB 6000896ull     /* bf16 xb[NIN][64] */
#define OFF_VALS 25200896ull  /* bf16 vals[KR][64] */
#define WS_FULL (25200896ull + 172800000ull) /* 198.0 MB */

__device__ __forceinline__ void gload_lds16(const void* g, void* l) {
  __builtin_amdgcn_global_load_lds(
      (const __attribute__((address_space(1))) unsigned int*)g,
      (__attribute__((address_space(3))) unsigned int*)l, 16, 0, 0);
}

// ---------------- x -> bf16, fused with off zeroing ----------------
__global__ __launch_bounds__(256) void k_cvt_zero(const float* __restrict__ x,
                                                  __bf16* __restrict__ xb,
                                                  int* __restrict__ cnt) {
  const int i = blockIdx.x * 256 + threadIdx.x;
  if (i < NIN * CIN / 8) {
    const float4 f0 = reinterpret_cast<const float4*>(x)[i * 2];
    const float4 f1 = reinterpret_cast<const float4*>(x)[i * 2 + 1];
    bf16x8_t v;
    v[0] = (__bf16)f0.x; v[1] = (__bf16)f0.y; v[2] = (__bf16)f0.z; v[3] = (__bf16)f0.w;
    v[4] = (__bf16)f1.x; v[5] = (__bf16)f1.y; v[6] = (__bf16)f1.z; v[7] = (__bf16)f1.w;
    reinterpret_cast<bf16x8_t*>(xb)[i] = v;
  }
  if (i <= NOUT) cnt[i] = 0;
}

// ---------------- sort kernels ----------------
__global__ __launch_bounds__(256) void k_count(const int* __restrict__ out_idx,
                                               int* __restrict__ cnt,
                                               int* __restrict__ rankl) {
  const int i = blockIdx.x * 256 + threadIdx.x;
  if (i < KR / 4) {
    const int4 v = reinterpret_cast<const int4*>(out_idx)[i];
    int4 r;
    r.x = atomicAdd(&cnt[v.x], 1);
    r.y = atomicAdd(&cnt[v.y], 1);
    r.z = atomicAdd(&cnt[v.z], 1);
    r.w = atomicAdd(&cnt[v.w], 1);
    reinterpret_cast<int4*>(rankl)[i] = r;
  }
}

__global__ __launch_bounds__(1024) void k_scan1(int* __restrict__ off,
                                                int* __restrict__ bsum) {
  __shared__ int s[1024];
  const int t = threadIdx.x;
  const int i = blockIdx.x * 1024 + t;
  const int v = (i < NOUT) ? off[i] : 0;
  s[t] = v;
  __syncthreads();
#pragma unroll
  for (int d = 1; d < 1024; d <<= 1) {
    const int u = (t >= d) ? s[t - d] : 0;
    __syncthreads();
    s[t] += u;
    __syncthreads();
  }
  if (i < NOUT) off[i] = s[t] - v;  // exclusive within block
  if (t == 1023) bsum[blockIdx.x] = s[1023];
}

// scan of bsum done redundantly per block in LDS (replaces scan2+scan3)
__global__ __launch_bounds__(256) void k_scan3(int* __restrict__ off,
                                               const int* __restrict__ bsum,
                                               int nb) {
  __shared__ int s[256];
  const int t = threadIdx.x;
  const int v = (t < nb) ? bsum[t] : 0;
  s[t] = v;
  __syncthreads();
#pragma unroll
  for (int d = 1; d < 256; d <<= 1) {
    const int u = (t >= d) ? s[t - d] : 0;
    __syncthreads();
    s[t] += u;
    __syncthreads();
  }
  // s[t] = inclusive sum; exclusive prefix for block b = s[b] - bsum[b]
  const int i = blockIdx.x * 256 + t;
  if (i < NOUT) {
    const int b = i >> 10;
    off[i] += s[b] - bsum[b];
  }
  if (i == 0) off[NOUT] = KR;
}

// ---------------- pass 1: bf16 gather via global_load_lds, BR=128 ----------------
__global__ __launch_bounds__(256) void pass1_bf16(
    const __bf16* __restrict__ xb, const float* __restrict__ w,
    const int* __restrict__ in_idx, const int* __restrict__ out_idx,
    const int* __restrict__ off_arr, const int* __restrict__ rankl,
    __bf16* __restrict__ vals) {
  __shared__ char lds[BR1 * 128 + 64 * 128];  // 24 KB
  __shared__ int lds_dst[BR1];
  char* const Abase = lds;
  char* const Bbase = lds + BR1 * 128;

  const int bid = blockIdx.x;
  const int k = bid / BPK1;
  const int rblk = bid - k * BPK1;
  const int rule0 = rblk * BR1;
  const int t = threadIdx.x;
  const int wid = t >> 6;
  const int lane = t & 63;

  // stage A: per-lane pre-swizzled source, linear LDS dest
  {
    const int rowInWave = lane >> 3;
    const int srcChunk = (lane & 7) ^ rowInWave;
    const int* idxBase = in_idx + (size_t)k * RULES;
#pragma unroll
    for (int it = 0; it < 4; ++it) {
      const int rbase = it * 32 + wid * 8;
      int rule = rule0 + rbase + rowInWave;
      if (rule > RULES - 1) rule = RULES - 1;  // clamp: finite data, skipped later
      const int src = idxBase[rule];
      const __bf16* gp = xb + ((size_t)src << 6) + (srcChunk << 3);
      gload_lds16(gp, Abase + rbase * 128 + lane * 16);
    }
  }

  // dst precompute (overlaps gather DMA): kills end-of-kernel dependent chain
  if (t < BR1) {
    const int rule = rule0 + t;
    if (rule < RULES) {
      const size_t gi = (size_t)k * RULES + rule;
      lds_dst[t] = off_arr[out_idx[gi]] + rankl[gi];
    }
  }

  // stage B: W_k^T -> LDS[o][c] bf16, swizzled
  {
    const int c = t >> 2;
    const int o0 = (t & 3) * 16;
    const float* wp = w + ((size_t)k * CIN + c) * COUT + o0;
#pragma unroll
    for (int j4 = 0; j4 < 4; ++j4) {
      const float4 f = *reinterpret_cast<const float4*>(wp + j4 * 4);
#pragma unroll
      for (int e = 0; e < 4; ++e) {
        const int o = o0 + j4 * 4 + e;
        const float val = (e == 0) ? f.x : (e == 1) ? f.y : (e == 2) ? f.z : f.w;
        const int addr = o * 128 + ((c * 2) ^ ((o & 7) << 4));
        *reinterpret_cast<__bf16*>(Bbase + addr) = (__bf16)val;
      }
    }
  }

  __syncthreads();

  const int rA = lane & 15;
  const int g = lane >> 4;

  bf16x8_t af[2][2];
  bf16x8_t bfr[4][2];
#pragma unroll
  for (int m = 0; m < 2; ++m)
#pragma unroll
    for (int kk = 0; kk < 2; ++kk) {
      const int r = wid * 32 + m * 16 + rA;
      const int colByte = (kk * 64 + g * 16) ^ ((r & 7) << 4);
      af[m][kk] = *reinterpret_cast<const bf16x8_t*>(Abase + r * 128 + colByte);
    }
#pragma unroll
  for (int n = 0; n < 4; ++n)
#pragma unroll
    for (int kk = 0; kk < 2; ++kk) {
      const int o = n * 16 + rA;
      const int colByte = (kk * 64 + g * 16) ^ ((o & 7) << 4);
      bfr[n][kk] = *reinterpret_cast<const bf16x8_t*>(Bbase + o * 128 + colByte);
    }

  __syncthreads();  // frag reads done; Abase reused for D staging

  f32x4_t acc[2][4];
#pragma unroll
  for (int m = 0; m < 2; ++m)
#pragma unroll
    for (int n = 0; n < 4; ++n)
#pragma unroll
      for (int e = 0; e < 4; ++e) acc[m][n][e] = 0.0f;

#pragma unroll
  for (int kk = 0; kk < 2; ++kk)
#pragma unroll
    for (int m = 0; m < 2; ++m)
#pragma unroll
      for (int n = 0; n < 4; ++n)
        acc[m][n] = __builtin_amdgcn_mfma_f32_16x16x32_bf16(
            af[m][kk], bfr[n][kk], acc[m][n], 0, 0, 0);

  // stage D -> LDS bf16 rows (swizzled)
  const bool evenLane = (rA & 1) == 0;
#pragma unroll
  for (int m = 0; m < 2; ++m) {
#pragma unroll
    for (int j = 0; j < 4; ++j) {
      const int rr = wid * 32 + m * 16 + g * 4 + j;
      float mine[4], other[4];
#pragma unroll
      for (int n = 0; n < 4; ++n) {
        mine[n] = acc[m][n][j];
        other[n] = __shfl_xor(mine[n], 1, 64);
      }
      const int swz = (rr & 7) << 4;
      if (evenLane) {
#pragma unroll
        for (int n = 0; n < 2; ++n) {
          bf16x2_t p; p[0] = (__bf16)mine[n]; p[1] = (__bf16)other[n];
          const int col = n * 16 + rA;
          *reinterpret_cast<bf16x2_t*>(Abase + rr * 128 + ((col * 2) ^ swz)) = p;
        }
      } else {
#pragma unroll
        for (int n = 2; n < 4; ++n) {
          bf16x2_t p; p[0] = (__bf16)other[n]; p[1] = (__bf16)mine[n];
          const int col = n * 16 + rA - 1;
          *reinterpret_cast<bf16x2_t*>(Abase + rr * 128 + ((col * 2) ^ swz)) = p;
        }
      }
    }
  }

  __syncthreads();

  // writeback: scatter full 128B rows to vals[lds_dst[r]]
  {
    const int chunk = t & 7;
    const int r0 = t >> 3;
#pragma unroll
    for (int pass = 0; pass < 4; ++pass) {
      const int r = r0 + pass * 32;
      const int rule = rule0 + r;
      if (rule < RULES) {
        const int dst = lds_dst[r];
        const bf16x8_t v = *reinterpret_cast<const bf16x8_t*>(
            Abase + r * 128 + ((chunk * 16) ^ ((r & 7) << 4)));
        *reinterpret_cast<bf16x8_t*>(vals + (size_t)dst * COUT + chunk * 8) = v;
      }
    }
  }
}

// ---------------- pass 2 v4: chunked LDS-stream, register accumulate ----------
__global__ __launch_bounds__(256) void pass2_kernel(
    const __bf16* __restrict__ vals, const int* __restrict__ off,
    const float* __restrict__ bias, float* __restrict__ out) {
  __shared__ __bf16 buf[P2CH * COUT];  // 32 KB
  __shared__ int soff[P2R + 1];

  const int t = threadIdx.x;
  const int row0 = blockIdx.x * P2R;

  if (t <= P2R) {
    int r = row0 + t;
    if (r > NOUT) r = NOUT;
    soff[t] = off[r];
  }
  __syncthreads();

  const int S = soff[0];
  const int E = soff[P2R];
  const int rloc = t >> 4;  // 0..15
  const int l16 = t & 15;   // 4-channel slice
  const int r0 = soff[rloc];
  const int r1 = soff[rloc + 1];

  const float4 b = reinterpret_cast<const float4*>(bias)[l16];
  float a0 = b.x, a1 = b.y, a2 = b.z, a3 = b.w;

  for (int base = S; base < E; base += P2CH) {
    const int n = min(P2CH, E - base);
    // stage n rules (n*128 B) coalesced: u-th 16B unit, dest = lane-linear
    for (int u = t; u < n * 8; u += 256)
      gload_lds16(vals + ((size_t)base << 6) + (size_t)u * 8,
                  (char*)buf + (size_t)u * 16);
    __syncthreads();  // drains vmcnt (compiler emits waitcnt before barrier)

    const int js = (r0 > base) ? r0 : base;
    const int je = (r1 < base + n) ? r1 : (base + n);
    const char* bp = (const char*)buf + (size_t)(js - base) * 128 + l16 * 8;
    for (int j = js; j < je; ++j, bp += 128) {
      const bf16x4_t v = *reinterpret_cast<const bf16x4_t*>(bp);
      a0 += (float)v[0];
      a1 += (float)v[1];
      a2 += (float)v[2];
      a3 += (float)v[3];
    }
    __syncthreads();
  }

  const int row = row0 + rloc;
  if (row < NOUT)
    reinterpret_cast<float4*>(out + (size_t)row * COUT)[l16] =
        make_float4(a0, a1, a2, a3);
}

// ---------------- fallback (tiny ws): atomic scatter ----------------
__global__ __launch_bounds__(256) void init_out_kernel(
    const float* __restrict__ bias, float* __restrict__ out, int total4) {
  const int i = blockIdx.x * blockDim.x + threadIdx.x;
  if (i < total4) {
    const float4 v = reinterpret_cast<const float4*>(bias)[i & 15];
    reinterpret_cast<float4*>(out)[i] = v;
  }
}

__global__ __launch_bounds__(256) void spconv_atomic_kernel(
    const float* __restrict__ x, const float* __restrict__ w,
    const int* __restrict__ in_idx, const int* __restrict__ out_idx,
    float* __restrict__ out) {
  __shared__ char lds[256 * 128 + 64 * 128];
  char* const Abase = lds;
  char* const Bbase = lds + 256 * 128;

  const int bid = blockIdx.x;
  const int k = bid / BPKF;
  const int rblk = bid - k * BPKF;
  const int rule0 = rblk * BRF;
  const int t = threadIdx.x;

  {
    const int chunk = t & 7;
    const int r0 = t >> 3;
#pragma unroll
    for (int pass = 0; pass < 8; ++pass) {
      const int r = r0 + pass * 32;
      const int rule = rule0 + r;
      bf16x8_t v;
      if (rule < RULES) {
        const int src = in_idx[(size_t)k * RULES + rule];
        const float* p = x + (size_t)src * CIN + chunk * 8;
        const float4 f0 = *reinterpret_cast<const float4*>(p);
        const float4 f1 = *reinterpret_cast<const float4*>(p + 4);
        v[0] = (__bf16)f0.x; v[1] = (__bf16)f0.y;
        v[2] = (__bf16)f0.z; v[3] = (__bf16)f0.w;
        v[4] = (__bf16)f1.x; v[5] = (__bf16)f1.y;
        v[6] = (__bf16)f1.z; v[7] = (__bf16)f1.w;
      } else {
#pragma unroll
        for (int e = 0; e < 8; ++e) v[e] = (__bf16)0.0f;
      }
      const int colByte = (chunk * 16) ^ ((r & 7) << 4);
      *reinterpret_cast<bf16x8_t*>(Abase + r * 128 + colByte) = v;
    }
  }
  {
    const int c = t >> 2;
    const int o0 = (t & 3) * 16;
    const float* wp = w + ((size_t)k * CIN + c) * COUT + o0;
#pragma unroll
    for (int j4 = 0; j4 < 4; ++j4) {
      const float4 f = *reinterpret_cast<const float4*>(wp + j4 * 4);
#pragma unroll
      for (int e = 0; e < 4; ++e) {
        const int o = o0 + j4 * 4 + e;
        const float val = (e == 0) ? f.x : (e == 1) ? f.y : (e == 2) ? f.z : f.w;
        const int addr = o * 128 + ((c * 2) ^ ((o & 7) << 4));
        *reinterpret_cast<__bf16*>(Bbase + addr) = (__bf16)val;
      }
    }
  }
  __syncthreads();

  const int wid = t >> 6;
  const int l = t & 63;
  const int rA = l & 15;
  const int g = l >> 4;

  bf16x8_t af[4][2];
  bf16x8_t bfr[4][2];
#pragma unroll
  for (int m = 0; m < 4; ++m)
#pragma unroll
    for (int kk = 0; kk < 2; ++kk) {
      const int r = wid * 64 + m * 16 + rA;
      const int colByte = (kk * 64 + g * 16) ^ ((r & 7) << 4);
      af[m][kk] = *reinterpret_cast<const bf16x8_t*>(Abase + r * 128 + colByte);
    }
#pragma unroll
  for (int n = 0; n < 4; ++n)
#pragma unroll
    for (int kk = 0; kk < 2; ++kk) {
      const int o = n * 16 + rA;
      const int colByte = (kk * 64 + g * 16) ^ ((o & 7) << 4);
      bfr[n][kk] = *reinterpret_cast<const bf16x8_t*>(Bbase + o * 128 + colByte);
    }

  f32x4_t acc[4][4];
#pragma unroll
  for (int m = 0; m < 4; ++m)
#pragma unroll
    for (int n = 0; n < 4; ++n)
#pragma unroll
      for (int e = 0; e < 4; ++e) acc[m][n][e] = 0.0f;

#pragma unroll
  for (int kk = 0; kk < 2; ++kk)
#pragma unroll
    for (int m = 0; m < 4; ++m)
#pragma unroll
      for (int n = 0; n < 4; ++n)
        acc[m][n] = __builtin_amdgcn_mfma_f32_16x16x32_bf16(
            af[m][kk], bfr[n][kk], acc[m][n], 0, 0, 0);

#pragma unroll
  for (int m = 0; m < 4; ++m)
#pragma unroll
    for (int j = 0; j < 4; ++j) {
      const int rr = wid * 64 + m * 16 + g * 4 + j;
      const int rule = rule0 + rr;
      if (rule < RULES) {
        const int orow = out_idx[(size_t)k * RULES + rule];
        float* op = out + (size_t)orow * COUT + rA;
#pragma unroll
        for (int n = 0; n < 4; ++n) atomicAdd(op + n * 16, acc[m][n][j]);
      }
    }
}

// ---------------- launch ----------------
extern "C" void kernel_launch(void* const* d_in, const int* in_sizes, int n_in,
                              void* d_out, int out_size, void* d_ws, size_t ws_size,
                              hipStream_t stream) {
  const float* x = (const float*)d_in[0];
  const float* w = (const float*)d_in[1];
  const float* bias = (const float*)d_in[2];
  const int* in_idx = (const int*)d_in[3];
  const int* out_idx = (const int*)d_in[4];
  float* out = (float*)d_out;

  if (ws_size >= WS_FULL) {
    char* ws = (char*)d_ws;
    int* off = (int*)(ws + OFF_OFF);
    int* bsum = (int*)(ws + OFF_BSUM);
    int* rankl = (int*)(ws + OFF_RANK);
    __bf16* xb = (__bf16*)(ws + OFF_XB);
    __bf16* vals = (__bf16*)(ws + OFF_VALS);

    const int nb1 = (NOUT + 1023) / 1024;  // 147
    k_cvt_zero<<<(NIN * CIN / 8 + 255) / 256, 256, 0, stream>>>(x, xb, off);
    k_count<<<(KR / 4 + 255) / 256, 256, 0, stream>>>(out_idx, off, rankl);
    k_scan1<<<nb1, 1024, 0, stream>>>(off, bsum);
    k_scan3<<<(NOUT + 255) / 256, 256, 0, stream>>>(off, bsum, nb1);
    pass1_bf16<<<KOFF * BPK1, 256, 0, stream>>>(xb, w, in_idx, out_idx, off,
                                                rankl, vals);
    pass2_kernel<<<(NOUT + P2R - 1) / P2R, 256, 0, stream>>>(vals, off, bias, out);
  } else {
    const int total4 = NOUT * COUT / 4;
    init_out_kernel<<<(total4 + 255) / 256, 256, 0, stream>>>(bias, out, total4);
    spconv_atomic_kernel<<<KOFF * BPKF, 256, 0, stream>>>(x, w, in_idx, out_idx, out);
  }
}

// Round 9
// 261.552 us; speedup vs baseline: 2.7943x; 1.0014x over previous
//
#include <hip/hip_runtime.h>
#include <hip/hip_bf16.h>

// Rulebook sparse conv, R9: fixed-capacity padded sort (3 kernels).
//   dst slot = out_row*32 + atomicAdd(&cursor[row],1)  (claimed inside pass1,
//   overlapped with gather DMA). Counts ~Poisson(9): P(row>32) ~ 5e-10.
//   Removes k_count/k_scan1/k_scan3 (~43us + 2 gaps). pass2: direct padded
//   segment reads, thread=(row,8ch), 16B/lane, register accumulate.
// Tiers: PAD (>=634MB ws) -> EXACT (R8 path, >=198MB) -> atomic fallback.

typedef __bf16 bf16x8_t __attribute__((ext_vector_type(8)));
typedef __bf16 bf16x4_t __attribute__((ext_vector_type(4)));
typedef __bf16 bf16x2_t __attribute__((ext_vector_type(2)));
typedef float f32x4_t __attribute__((ext_vector_type(4)));

#define KOFF 27
#define RULES 50000
#define KR (KOFF * RULES) /* 1,350,000 */
#define CIN 64
#define COUT 64
#define NIN 150000
#define NOUT 150000
#define CAP 32  /* padded slots per out row */

// pass1 tile
#define BR1 128
#define BPK1 ((RULES + BR1 - 1) / BR1) /* 391 */
// exact-tier pass2 tile
#define P2R 16
#define P2CH 256
// fallback tile
#define BRF 256
#define BPKF ((RULES + BRF - 1) / BRF) /* 196 */

// ---- padded-tier ws layout ----
#define PAD_XB 0ull                 /* bf16 xb[NIN][64] : 19,200,000 */
#define PAD_CUR 19200000ull         /* int cursor[NOUT] : 600,000 */
#define PAD_VALS 19800064ull        /* bf16 vals[NOUT*CAP][64] : 614,400,000 */
#define WS_PAD (19800064ull + 614400000ull) /* 634.2 MB */

// ---- exact-tier ws layout (R8) ----
#define OFF_OFF 0ull
#define OFF_BSUM 600064ull
#define OFF_RANK 600832ull
#define OFF_XB 6000896ull
#define OFF_VALS 25200896ull
#define WS_FULL (25200896ull + 172800000ull) /* 198.0 MB */

__device__ __forceinline__ void gload_lds16(const void* g, void* l) {
  __builtin_amdgcn_global_load_lds(
      (const __attribute__((address_space(1))) unsigned int*)g,
      (__attribute__((address_space(3))) unsigned int*)l, 16, 0, 0);
}

// ---------------- x -> bf16, fused with zeroing ----------------
__global__ __launch_bounds__(256) void k_cvt_zero(const float* __restrict__ x,
                                                  __bf16* __restrict__ xb,
                                                  int* __restrict__ cnt,
                                                  int ncnt) {
  const int i = blockIdx.x * 256 + threadIdx.x;
  if (i < NIN * CIN / 8) {
    const float4 f0 = reinterpret_cast<const float4*>(x)[i * 2];
    const float4 f1 = reinterpret_cast<const float4*>(x)[i * 2 + 1];
    bf16x8_t v;
    v[0] = (__bf16)f0.x; v[1] = (__bf16)f0.y; v[2] = (__bf16)f0.z; v[3] = (__bf16)f0.w;
    v[4] = (__bf16)f1.x; v[5] = (__bf16)f1.y; v[6] = (__bf16)f1.z; v[7] = (__bf16)f1.w;
    reinterpret_cast<bf16x8_t*>(xb)[i] = v;
  }
  if (i < ncnt) cnt[i] = 0;
}

// ================= PADDED TIER =================
__global__ __launch_bounds__(256) void pass1_pad(
    const __bf16* __restrict__ xb, const float* __restrict__ w,
    const int* __restrict__ in_idx, const int* __restrict__ out_idx,
    int* __restrict__ cursor, __bf16* __restrict__ vals) {
  __shared__ char lds[BR1 * 128 + 64 * 128];  // 24 KB
  __shared__ int lds_dst[BR1];
  char* const Abase = lds;
  char* const Bbase = lds + BR1 * 128;

  const int bid = blockIdx.x;
  const int k = bid / BPK1;
  const int rblk = bid - k * BPK1;
  const int rule0 = rblk * BR1;
  const int t = threadIdx.x;
  const int wid = t >> 6;
  const int lane = t & 63;

  // stage A: per-lane pre-swizzled source, linear LDS dest
  {
    const int rowInWave = lane >> 3;
    const int srcChunk = (lane & 7) ^ rowInWave;
    const int* idxBase = in_idx + (size_t)k * RULES;
#pragma unroll
    for (int it = 0; it < 4; ++it) {
      const int rbase = it * 32 + wid * 8;
      int rule = rule0 + rbase + rowInWave;
      if (rule > RULES - 1) rule = RULES - 1;  // clamp: finite data, skipped later
      const int src = idxBase[rule];
      const __bf16* gp = xb + ((size_t)src << 6) + (srcChunk << 3);
      gload_lds16(gp, Abase + rbase * 128 + lane * 16);
    }
  }

  // slot claim (overlaps gather DMA): dst = row*CAP + rank
  if (t < BR1) {
    const int rule = rule0 + t;
    if (rule < RULES) {
      const int orow = out_idx[(size_t)k * RULES + rule];
      const int rank = atomicAdd(&cursor[orow], 1);
      lds_dst[t] = orow * CAP + rank;
    }
  }

  // stage B: W_k^T -> LDS[o][c] bf16, swizzled
  {
    const int c = t >> 2;
    const int o0 = (t & 3) * 16;
    const float* wp = w + ((size_t)k * CIN + c) * COUT + o0;
#pragma unroll
    for (int j4 = 0; j4 < 4; ++j4) {
      const float4 f = *reinterpret_cast<const float4*>(wp + j4 * 4);
#pragma unroll
      for (int e = 0; e < 4; ++e) {
        const int o = o0 + j4 * 4 + e;
        const float val = (e == 0) ? f.x : (e == 1) ? f.y : (e == 2) ? f.z : f.w;
        const int addr = o * 128 + ((c * 2) ^ ((o & 7) << 4));
        *reinterpret_cast<__bf16*>(Bbase + addr) = (__bf16)val;
      }
    }
  }

  __syncthreads();

  const int rA = lane & 15;
  const int g = lane >> 4;

  bf16x8_t af[2][2];
  bf16x8_t bfr[4][2];
#pragma unroll
  for (int m = 0; m < 2; ++m)
#pragma unroll
    for (int kk = 0; kk < 2; ++kk) {
      const int r = wid * 32 + m * 16 + rA;
      const int colByte = (kk * 64 + g * 16) ^ ((r & 7) << 4);
      af[m][kk] = *reinterpret_cast<const bf16x8_t*>(Abase + r * 128 + colByte);
    }
#pragma unroll
  for (int n = 0; n < 4; ++n)
#pragma unroll
    for (int kk = 0; kk < 2; ++kk) {
      const int o = n * 16 + rA;
      const int colByte = (kk * 64 + g * 16) ^ ((o & 7) << 4);
      bfr[n][kk] = *reinterpret_cast<const bf16x8_t*>(Bbase + o * 128 + colByte);
    }

  __syncthreads();  // frag reads done; Abase reused for D staging

  f32x4_t acc[2][4];
#pragma unroll
  for (int m = 0; m < 2; ++m)
#pragma unroll
    for (int n = 0; n < 4; ++n)
#pragma unroll
      for (int e = 0; e < 4; ++e) acc[m][n][e] = 0.0f;

#pragma unroll
  for (int kk = 0; kk < 2; ++kk)
#pragma unroll
    for (int m = 0; m < 2; ++m)
#pragma unroll
      for (int n = 0; n < 4; ++n)
        acc[m][n] = __builtin_amdgcn_mfma_f32_16x16x32_bf16(
            af[m][kk], bfr[n][kk], acc[m][n], 0, 0, 0);

  // stage D -> LDS bf16 rows (swizzled)
  const bool evenLane = (rA & 1) == 0;
#pragma unroll
  for (int m = 0; m < 2; ++m) {
#pragma unroll
    for (int j = 0; j < 4; ++j) {
      const int rr = wid * 32 + m * 16 + g * 4 + j;
      float mine[4], other[4];
#pragma unroll
      for (int n = 0; n < 4; ++n) {
        mine[n] = acc[m][n][j];
        other[n] = __shfl_xor(mine[n], 1, 64);
      }
      const int swz = (rr & 7) << 4;
      if (evenLane) {
#pragma unroll
        for (int n = 0; n < 2; ++n) {
          bf16x2_t p; p[0] = (__bf16)mine[n]; p[1] = (__bf16)other[n];
          const int col = n * 16 + rA;
          *reinterpret_cast<bf16x2_t*>(Abase + rr * 128 + ((col * 2) ^ swz)) = p;
        }
      } else {
#pragma unroll
        for (int n = 2; n < 4; ++n) {
          bf16x2_t p; p[0] = (__bf16)other[n]; p[1] = (__bf16)mine[n];
          const int col = n * 16 + rA - 1;
          *reinterpret_cast<bf16x2_t*>(Abase + rr * 128 + ((col * 2) ^ swz)) = p;
        }
      }
    }
  }

  __syncthreads();

  // writeback: scatter full 128B rows to vals[lds_dst[r]]
  {
    const int chunk = t & 7;
    const int r0 = t >> 3;
#pragma unroll
    for (int pass = 0; pass < 4; ++pass) {
      const int r = r0 + pass * 32;
      const int rule = rule0 + r;
      if (rule < RULES) {
        const size_t dst = (size_t)lds_dst[r];
        const bf16x8_t v = *reinterpret_cast<const bf16x8_t*>(
            Abase + r * 128 + ((chunk * 16) ^ ((r & 7) << 4)));
        *reinterpret_cast<bf16x8_t*>(vals + dst * COUT + chunk * 8) = v;
      }
    }
  }
}

// pass2: thread=(row, 8ch); wave = 8 rows x 8 lanes; 16B/lane reads.
__global__ __launch_bounds__(256) void pass2_pad(
    const __bf16* __restrict__ vals, const int* __restrict__ cursor,
    const float* __restrict__ bias, float* __restrict__ out) {
  const int t = threadIdx.x;
  const int rloc = t >> 3;   // 0..31
  const int l8 = t & 7;      // 8-channel slice
  const int row = blockIdx.x * 32 + rloc;
  if (row >= NOUT) return;

  const float4 b0 = reinterpret_cast<const float4*>(bias)[l8 * 2];
  const float4 b1 = reinterpret_cast<const float4*>(bias)[l8 * 2 + 1];
  float a0 = b0.x, a1 = b0.y, a2 = b0.z, a3 = b0.w;
  float a4 = b1.x, a5 = b1.y, a6 = b1.z, a7 = b1.w;

  const int cnt = cursor[row];
  const __bf16* vp = vals + ((size_t)row * CAP) * COUT + l8 * 8;
  for (int j = 0; j < cnt; ++j, vp += COUT) {
    const bf16x8_t v = *reinterpret_cast<const bf16x8_t*>(vp);
    a0 += (float)v[0]; a1 += (float)v[1]; a2 += (float)v[2]; a3 += (float)v[3];
    a4 += (float)v[4]; a5 += (float)v[5]; a6 += (float)v[6]; a7 += (float)v[7];
  }
  float* op = out + (size_t)row * COUT + l8 * 8;
  reinterpret_cast<float4*>(op)[0] = make_float4(a0, a1, a2, a3);
  reinterpret_cast<float4*>(op)[1] = make_float4(a4, a5, a6, a7);
}

// ================= EXACT TIER (R8) =================
__global__ __launch_bounds__(256) void k_count(const int* __restrict__ out_idx,
                                               int* __restrict__ cnt,
                                               int* __restrict__ rankl) {
  const int i = blockIdx.x * 256 + threadIdx.x;
  if (i < KR / 4) {
    const int4 v = reinterpret_cast<const int4*>(out_idx)[i];
    int4 r;
    r.x = atomicAdd(&cnt[v.x], 1);
    r.y = atomicAdd(&cnt[v.y], 1);
    r.z = atomicAdd(&cnt[v.z], 1);
    r.w = atomicAdd(&cnt[v.w], 1);
    reinterpret_cast<int4*>(rankl)[i] = r;
  }
}

__global__ __launch_bounds__(1024) void k_scan1(int* __restrict__ off,
                                                int* __restrict__ bsum) {
  __shared__ int s[1024];
  const int t = threadIdx.x;
  const int i = blockIdx.x * 1024 + t;
  const int v = (i < NOUT) ? off[i] : 0;
  s[t] = v;
  __syncthreads();
#pragma unroll
  for (int d = 1; d < 1024; d <<= 1) {
    const int u = (t >= d) ? s[t - d] : 0;
    __syncthreads();
    s[t] += u;
    __syncthreads();
  }
  if (i < NOUT) off[i] = s[t] - v;
  if (t == 1023) bsum[blockIdx.x] = s[1023];
}

__global__ __launch_bounds__(256) void k_scan3(int* __restrict__ off,
                                               const int* __restrict__ bsum,
                                               int nb) {
  __shared__ int s[256];
  const int t = threadIdx.x;
  const int v = (t < nb) ? bsum[t] : 0;
  s[t] = v;
  __syncthreads();
#pragma unroll
  for (int d = 1; d < 256; d <<= 1) {
    const int u = (t >= d) ? s[t - d] : 0;
    __syncthreads();
    s[t] += u;
    __syncthreads();
  }
  const int i = blockIdx.x * 256 + t;
  if (i < NOUT) {
    const int b = i >> 10;
    off[i] += s[b] - bsum[b];
  }
  if (i == 0) off[NOUT] = KR;
}

__global__ __launch_bounds__(256) void pass1_bf16(
    const __bf16* __restrict__ xb, const float* __restrict__ w,
    const int* __restrict__ in_idx, const int* __restrict__ out_idx,
    const int* __restrict__ off_arr, const int* __restrict__ rankl,
    __bf16* __restrict__ vals) {
  __shared__ char lds[BR1 * 128 + 64 * 128];
  __shared__ int lds_dst[BR1];
  char* const Abase = lds;
  char* const Bbase = lds + BR1 * 128;

  const int bid = blockIdx.x;
  const int k = bid / BPK1;
  const int rblk = bid - k * BPK1;
  const int rule0 = rblk * BR1;
  const int t = threadIdx.x;
  const int wid = t >> 6;
  const int lane = t & 63;

  {
    const int rowInWave = lane >> 3;
    const int srcChunk = (lane & 7) ^ rowInWave;
    const int* idxBase = in_idx + (size_t)k * RULES;
#pragma unroll
    for (int it = 0; it < 4; ++it) {
      const int rbase = it * 32 + wid * 8;
      int rule = rule0 + rbase + rowInWave;
      if (rule > RULES - 1) rule = RULES - 1;
      const int src = idxBase[rule];
      const __bf16* gp = xb + ((size_t)src << 6) + (srcChunk << 3);
      gload_lds16(gp, Abase + rbase * 128 + lane * 16);
    }
  }

  if (t < BR1) {
    const int rule = rule0 + t;
    if (rule < RULES) {
      const size_t gi = (size_t)k * RULES + rule;
      lds_dst[t] = off_arr[out_idx[gi]] + rankl[gi];
    }
  }

  {
    const int c = t >> 2;
    const int o0 = (t & 3) * 16;
    const float* wp = w + ((size_t)k * CIN + c) * COUT + o0;
#pragma unroll
    for (int j4 = 0; j4 < 4; ++j4) {
      const float4 f = *reinterpret_cast<const float4*>(wp + j4 * 4);
#pragma unroll
      for (int e = 0; e < 4; ++e) {
        const int o = o0 + j4 * 4 + e;
        const float val = (e == 0) ? f.x : (e == 1) ? f.y : (e == 2) ? f.z : f.w;
        const int addr = o * 128 + ((c * 2) ^ ((o & 7) << 4));
        *reinterpret_cast<__bf16*>(Bbase + addr) = (__bf16)val;
      }
    }
  }

  __syncthreads();

  const int rA = lane & 15;
  const int g = lane >> 4;

  bf16x8_t af[2][2];
  bf16x8_t bfr[4][2];
#pragma unroll
  for (int m = 0; m < 2; ++m)
#pragma unroll
    for (int kk = 0; kk < 2; ++kk) {
      const int r = wid * 32 + m * 16 + rA;
      const int colByte = (kk * 64 + g * 16) ^ ((r & 7) << 4);
      af[m][kk] = *reinterpret_cast<const bf16x8_t*>(Abase + r * 128 + colByte);
    }
#pragma unroll
  for (int n = 0; n < 4; ++n)
#pragma unroll
    for (int kk = 0; kk < 2; ++kk) {
      const int o = n * 16 + rA;
      const int colByte = (kk * 64 + g * 16) ^ ((o & 7) << 4);
      bfr[n][kk] = *reinterpret_cast<const bf16x8_t*>(Bbase + o * 128 + colByte);
    }

  __syncthreads();

  f32x4_t acc[2][4];
#pragma unroll
  for (int m = 0; m < 2; ++m)
#pragma unroll
    for (int n = 0; n < 4; ++n)
#pragma unroll
      for (int e = 0; e < 4; ++e) acc[m][n][e] = 0.0f;

#pragma unroll
  for (int kk = 0; kk < 2; ++kk)
#pragma unroll
    for (int m = 0; m < 2; ++m)
#pragma unroll
      for (int n = 0; n < 4; ++n)
        acc[m][n] = __builtin_amdgcn_mfma_f32_16x16x32_bf16(
            af[m][kk], bfr[n][kk], acc[m][n], 0, 0, 0);

  const bool evenLane = (rA & 1) == 0;
#pragma unroll
  for (int m = 0; m < 2; ++m) {
#pragma unroll
    for (int j = 0; j < 4; ++j) {
      const int rr = wid * 32 + m * 16 + g * 4 + j;
      float mine[4], other[4];
#pragma unroll
      for (int n = 0; n < 4; ++n) {
        mine[n] = acc[m][n][j];
        other[n] = __shfl_xor(mine[n], 1, 64);
      }
      const int swz = (rr & 7) << 4;
      if (evenLane) {
#pragma unroll
        for (int n = 0; n < 2; ++n) {
          bf16x2_t p; p[0] = (__bf16)mine[n]; p[1] = (__bf16)other[n];
          const int col = n * 16 + rA;
          *reinterpret_cast<bf16x2_t*>(Abase + rr * 128 + ((col * 2) ^ swz)) = p;
        }
      } else {
#pragma unroll
        for (int n = 2; n < 4; ++n) {
          bf16x2_t p; p[0] = (__bf16)other[n]; p[1] = (__bf16)mine[n];
          const int col = n * 16 + rA - 1;
          *reinterpret_cast<bf16x2_t*>(Abase + rr * 128 + ((col * 2) ^ swz)) = p;
        }
      }
    }
  }

  __syncthreads();

  {
    const int chunk = t & 7;
    const int r0 = t >> 3;
#pragma unroll
    for (int pass = 0; pass < 4; ++pass) {
      const int r = r0 + pass * 32;
      const int rule = rule0 + r;
      if (rule < RULES) {
        const int dst = lds_dst[r];
        const bf16x8_t v = *reinterpret_cast<const bf16x8_t*>(
            Abase + r * 128 + ((chunk * 16) ^ ((r & 7) << 4)));
        *reinterpret_cast<bf16x8_t*>(vals + (size_t)dst * COUT + chunk * 8) = v;
      }
    }
  }
}

__global__ __launch_bounds__(256) void pass2_kernel(
    const __bf16* __restrict__ vals, const int* __restrict__ off,
    const float* __restrict__ bias, float* __restrict__ out) {
  __shared__ __bf16 buf[P2CH * COUT];
  __shared__ int soff[P2R + 1];

  const int t = threadIdx.x;
  const int row0 = blockIdx.x * P2R;

  if (t <= P2R) {
    int r = row0 + t;
    if (r > NOUT) r = NOUT;
    soff[t] = off[r];
  }
  __syncthreads();

  const int S = soff[0];
  const int E = soff[P2R];
  const int rloc = t >> 4;
  const int l16 = t & 15;
  const int r0 = soff[rloc];
  const int r1 = soff[rloc + 1];

  const float4 b = reinterpret_cast<const float4*>(bias)[l16];
  float a0 = b.x, a1 = b.y, a2 = b.z, a3 = b.w;

  for (int base = S; base < E; base += P2CH) {
    const int n = min(P2CH, E - base);
    for (int u = t; u < n * 8; u += 256)
      gload_lds16(vals + ((size_t)base << 6) + (size_t)u * 8,
                  (char*)buf + (size_t)u * 16);
    __syncthreads();

    const int js = (r0 > base) ? r0 : base;
    const int je = (r1 < base + n) ? r1 : (base + n);
    const char* bp = (const char*)buf + (size_t)(js - base) * 128 + l16 * 8;
    for (int j = js; j < je; ++j, bp += 128) {
      const bf16x4_t v = *reinterpret_cast<const bf16x4_t*>(bp);
      a0 += (float)v[0];
      a1 += (float)v[1];
      a2 += (float)v[2];
      a3 += (float)v[3];
    }
    __syncthreads();
  }

  const int row = row0 + rloc;
  if (row < NOUT)
    reinterpret_cast<float4*>(out + (size_t)row * COUT)[l16] =
        make_float4(a0, a1, a2, a3);
}

// ================= ATOMIC FALLBACK =================
__global__ __launch_bounds__(256) void init_out_kernel(
    const float* __restrict__ bias, float* __restrict__ out, int total4) {
  const int i = blockIdx.x * blockDim.x + threadIdx.x;
  if (i < total4) {
    const float4 v = reinterpret_cast<const float4*>(bias)[i & 15];
    reinterpret_cast<float4*>(out)[i] = v;
  }
}

__global__ __launch_bounds__(256) void spconv_atomic_kernel(
    const float* __restrict__ x, const float* __restrict__ w,
    const int* __restrict__ in_idx, const int* __restrict__ out_idx,
    float* __restrict__ out) {
  __shared__ char lds[256 * 128 + 64 * 128];
  char* const Abase = lds;
  char* const Bbase = lds + 256 * 128;

  const int bid = blockIdx.x;
  const int k = bid / BPKF;
  const int rblk = bid - k * BPKF;
  const int rule0 = rblk * BRF;
  const int t = threadIdx.x;

  {
    const int chunk = t & 7;
    const int r0 = t >> 3;
#pragma unroll
    for (int pass = 0; pass < 8; ++pass) {
      const int r = r0 + pass * 32;
      const int rule = rule0 + r;
      bf16x8_t v;
      if (rule < RULES) {
        const int src = in_idx[(size_t)k * RULES + rule];
        const float* p = x + (size_t)src * CIN + chunk * 8;
        const float4 f0 = *reinterpret_cast<const float4*>(p);
        const float4 f1 = *reinterpret_cast<const float4*>(p + 4);
        v[0] = (__bf16)f0.x; v[1] = (__bf16)f0.y;
        v[2] = (__bf16)f0.z; v[3] = (__bf16)f0.w;
        v[4] = (__bf16)f1.x; v[5] = (__bf16)f1.y;
        v[6] = (__bf16)f1.z; v[7] = (__bf16)f1.w;
      } else {
#pragma unroll
        for (int e = 0; e < 8; ++e) v[e] = (__bf16)0.0f;
      }
      const int colByte = (chunk * 16) ^ ((r & 7) << 4);
      *reinterpret_cast<bf16x8_t*>(Abase + r * 128 + colByte) = v;
    }
  }
  {
    const int c = t >> 2;
    const int o0 = (t & 3) * 16;
    const float* wp = w + ((size_t)k * CIN + c) * COUT + o0;
#pragma unroll
    for (int j4 = 0; j4 < 4; ++j4) {
      const float4 f = *reinterpret_cast<const float4*>(wp + j4 * 4);
#pragma unroll
      for (int e = 0; e < 4; ++e) {
        const int o = o0 + j4 * 4 + e;
        const float val = (e == 0) ? f.x : (e == 1) ? f.y : (e == 2) ? f.z : f.w;
        const int addr = o * 128 + ((c * 2) ^ ((o & 7) << 4));
        *reinterpret_cast<__bf16*>(Bbase + addr) = (__bf16)val;
      }
    }
  }
  __syncthreads();

  const int wid = t >> 6;
  const int l = t & 63;
  const int rA = l & 15;
  const int g = l >> 4;

  bf16x8_t af[4][2];
  bf16x8_t bfr[4][2];
#pragma unroll
  for (int m = 0; m < 4; ++m)
#pragma unroll
    for (int kk = 0; kk < 2; ++kk) {
      const int r = wid * 64 + m * 16 + rA;
      const int colByte = (kk * 64 + g * 16) ^ ((r & 7) << 4);
      af[m][kk] = *reinterpret_cast<const bf16x8_t*>(Abase + r * 128 + colByte);
    }
#pragma unroll
  for (int n = 0; n < 4; ++n)
#pragma unroll
    for (int kk = 0; kk < 2; ++kk) {
      const int o = n * 16 + rA;
      const int colByte = (kk * 64 + g * 16) ^ ((o & 7) << 4);
      bfr[n][kk] = *reinterpret_cast<const bf16x8_t*>(Bbase + o * 128 + colByte);
    }

  f32x4_t acc[4][4];
#pragma unroll
  for (int m = 0; m < 4; ++m)
#pragma unroll
    for (int n = 0; n < 4; ++n)
#pragma unroll
      for (int e = 0; e < 4; ++e) acc[m][n][e] = 0.0f;

#pragma unroll
  for (int kk = 0; kk < 2; ++kk)
#pragma unroll
    for (int m = 0; m < 4; ++m)
#pragma unroll
      for (int n = 0; n < 4; ++n)
        acc[m][n] = __builtin_amdgcn_mfma_f32_16x16x32_bf16(
            af[m][kk], bfr[n][kk], acc[m][n], 0, 0, 0);

#pragma unroll
  for (int m = 0; m < 4; ++m)
#pragma unroll
    for (int j = 0; j < 4; ++j) {
      const int rr = wid * 64 + m * 16 + g * 4 + j;
      const int rule = rule0 + rr;
      if (rule < RULES) {
        const int orow = out_idx[(size_t)k * RULES + rule];
        float* op = out + (size_t)orow * COUT + rA;
#pragma unroll
        for (int n = 0; n < 4; ++n) atomicAdd(op + n * 16, acc[m][n][j]);
      }
    }
}

// ---------------- launch ----------------
extern "C" void kernel_launch(void* const* d_in, const int* in_sizes, int n_in,
                              void* d_out, int out_size, void* d_ws, size_t ws_size,
                              hipStream_t stream) {
  const float* x = (const float*)d_in[0];
  const float* w = (const float*)d_in[1];
  const float* bias = (const float*)d_in[2];
  const int* in_idx = (const int*)d_in[3];
  const int* out_idx = (const int*)d_in[4];
  float* out = (float*)d_out;

  if (ws_size >= WS_PAD) {
    char* ws = (char*)d_ws;
    __bf16* xb = (__bf16*)(ws + PAD_XB);
    int* cursor = (int*)(ws + PAD_CUR);
    __bf16* vals = (__bf16*)(ws + PAD_VALS);

    k_cvt_zero<<<(NIN * CIN / 8 + 255) / 256, 256, 0, stream>>>(x, xb, cursor,
                                                                NOUT);
    pass1_pad<<<KOFF * BPK1, 256, 0, stream>>>(xb, w, in_idx, out_idx, cursor,
                                               vals);
    pass2_pad<<<(NOUT + 31) / 32, 256, 0, stream>>>(vals, cursor, bias, out);
  } else if (ws_size >= WS_FULL) {
    char* ws = (char*)d_ws;
    int* off = (int*)(ws + OFF_OFF);
    int* bsum = (int*)(ws + OFF_BSUM);
    int* rankl = (int*)(ws + OFF_RANK);
    __bf16* xb = (__bf16*)(ws + OFF_XB);
    __bf16* vals = (__bf16*)(ws + OFF_VALS);

    const int nb1 = (NOUT + 1023) / 1024;  // 147
    k_cvt_zero<<<(NIN * CIN / 8 + 255) / 256, 256, 0, stream>>>(x, xb, off,
                                                                NOUT + 1);
    k_count<<<(KR / 4 + 255) / 256, 256, 0, stream>>>(out_idx, off, rankl);
    k_scan1<<<nb1, 1024, 0, stream>>>(off, bsum);
    k_scan3<<<(NOUT + 255) / 256, 256, 0, stream>>>(off, bsum, nb1);
    pass1_bf16<<<KOFF * BPK1, 256, 0, stream>>>(xb, w, in_idx, out_idx, off,
                                                rankl, vals);
    pass2_kernel<<<(NOUT + P2R - 1) / P2R, 256, 0, stream>>>(vals, off, bias, out);
  } else {
    const int total4 = NOUT * COUT / 4;
    init_out_kernel<<<(total4 + 255) / 256, 256, 0, stream>>>(bias, out, total4);
    spconv_atomic_kernel<<<KOFF * BPKF, 256, 0, stream>>>(x, w, in_idx, out_idx, out);
  }
}